// Round 4
// baseline (244.007 us; speedup 1.0000x reference)
//
#include <hip/hip_runtime.h>

#define DIMX 512
#define HEADSX 4
#define DHX 128
#define CHX 16
#define NCX 128
#define SX 2048
#define BX 2
#define BHX 8
#define PADF 136   // stage LDS row pad (ushorts): multiple of 8 for aligned b128

typedef unsigned short ushort_t;
typedef unsigned int uint_t;
typedef short bf16x8 __attribute__((ext_vector_type(8)));
typedef float f32x4 __attribute__((ext_vector_type(4)));

__device__ __forceinline__ float sigmoidf_(float z){ return 1.0f/(1.0f + __expf(-z)); }

// fp32 -> bf16 round-to-nearest-even
__device__ __forceinline__ ushort_t f2bf(float f){
  uint_t u = __float_as_uint(f);
  return (ushort_t)((u + 0x7FFFu + ((u >> 16) & 1u)) >> 16);
}
__device__ __forceinline__ uint_t pk2(float a, float b){
  return (uint_t)f2bf(a) | ((uint_t)f2bf(b) << 16);
}

// ---------------- K-prep: bf16 weight layouts (+ scale folding) ----------------
// blocks 0..63 : WkvT[h][kt][col][kk] = f2bf(scale[d] * Wkv[d][wcol]), d = kt*32+kk
// blocks 64..71: per-bh w0T/w1T (transposed), w1n (natural)
// block  72    : wfs{S,M,D}[h*512+d] = scale[d] * W{step,mom,dec}[d][h]
__global__ __launch_bounds__(256) void k_prep(const float* __restrict__ Wkv,
    const float* __restrict__ w0, const float* __restrict__ w1,
    const float* __restrict__ scale,
    const float* __restrict__ Wstep, const float* __restrict__ Wmom,
    const float* __restrict__ Wdec,
    ushort_t* __restrict__ WkvT, ushort_t* __restrict__ w0T,
    ushort_t* __restrict__ w1T, ushort_t* __restrict__ w1n,
    float* __restrict__ wfsS, float* __restrict__ wfsM, float* __restrict__ wfsD){
  int blk = blockIdx.x; int tid = threadIdx.x;
  if (blk < 64){
    int h = blk >> 4, kt = blk & 15;
    __shared__ ushort_t tile[256][33];   // [col][kk], +1 pad
    for (int i=tid; i<8192; i+=256){
      int kk = i >> 8, col = i & 255;    // consecutive i -> consecutive col: coalesced read
      int d = kt*32 + kk;
      int wcol = (col < 128) ? (h*128 + col) : (384 + h*128 + col);
      float v = scale[d] * Wkv[(size_t)d*1024 + wcol];
      tile[col][kk] = f2bf(v);
    }
    __syncthreads();
    for (int i=tid; i<8192; i+=256){
      int col = i >> 5, kk = i & 31;     // consecutive i -> consecutive kk: coalesced write
      WkvT[(((size_t)h*16 + kt)*256 + col)*32 + kk] = tile[col][kk];
    }
  } else if (blk < 72){
    int bh = blk - 64;
    size_t base = (size_t)bh*16384;
    for (int i=tid; i<16384; i+=256){
      int r = i >> 7, c = i & 127;
      w0T[base + i] = f2bf(w0[base + (size_t)c*128 + r]);
      w1T[base + i] = f2bf(w1[base + (size_t)c*128 + r]);
      w1n[base + i] = f2bf(w1[base + i]);
    }
  } else {
    for (int i=tid; i<2048; i+=256){
      int d = i & 511, h = i >> 9;
      float sc = scale[d];
      wfsS[i] = sc * Wstep[d*4 + h];
      wfsM[i] = sc * Wmom [d*4 + h];
      wfsD[i] = sc * Wdec [d*4 + h];
    }
  }
}

// ---------------- K-fused3: barrier-free per-wave chunk pipeline ----------------
// 256 blocks x 256 threads; wave w of block blk owns chunk (bh = blk&7,
// t = (blk>>3)*4 + w). Everything is wave-local: seq is streamed twice in MFMA
// fragment layout (lane = token l&15, dims kt*32+quad*8), so there is no xs
// LDS staging and ZERO __syncthreads. Stage buffers (k, a, dp, dh) are
// per-wave LDS slices; same-wave LDS RAW ordering comes from compiler lgkmcnt.
__global__ __launch_bounds__(256) void k_fused3(const float* __restrict__ seq,
    const float* __restrict__ wfsS, const float* __restrict__ wfsM,
    const float* __restrict__ wfsD,
    const ushort_t* __restrict__ WkvT, const ushort_t* __restrict__ w0T,
    const ushort_t* __restrict__ w1T, const ushort_t* __restrict__ w1n,
    ushort_t* __restrict__ fac0, ushort_t* __restrict__ fac1,
    float* __restrict__ momw, float* __restrict__ decw){
  int blk = blockIdx.x;
  int bh = blk & 7, tq = blk >> 3;
  int b = bh >> 2, h = bh & 3;
  int tid = threadIdx.x;
  int wv = tid >> 6, lane = tid & 63;
  int t = tq*4 + wv;
  int bt = bh*NCX + t;
  int quad = lane >> 4, nl = lane & 15;
  const f32x4 zero = {0.f,0.f,0.f,0.f};

  __shared__ __align__(16) ushort_t ks_[4][16*PADF];
  __shared__ __align__(16) ushort_t as_[4][16*PADF];
  __shared__ __align__(16) ushort_t dp_[4][16*PADF];
  __shared__ __align__(16) ushort_t dh_[4][16*PADF];
  __shared__ float lr_s[4][16];
  ushort_t* ksw = ks_[wv]; ushort_t* asw = as_[wv];
  ushort_t* dpw = dp_[wv]; ushort_t* dhw = dh_[wv];

  // lane's seq slice: token c = nl, dims kt*32 + quad*8 .. +7
  const float* sq = seq + ((size_t)(b*SX + t*CHX) + nl)*DIMX + quad*8;
  const float* wS = wfsS + h*512 + quad*8;
  const float* wM = wfsM + h*512 + quad*8;
  const float* wD = wfsD + h*512 + quad*8;

  // ---- pass A: reductions (rs, lr, mom, dec)
  float ss=0.f, lp=0.f, pm=0.f, pd=0.f;
  #pragma unroll
  for (int kt=0; kt<16; kt++){
    float4 q0 = *(const float4*)(sq + kt*32);
    float4 q1 = *(const float4*)(sq + kt*32 + 4);
    float4 s0 = *(const float4*)(wS + kt*32);
    float4 s1 = *(const float4*)(wS + kt*32 + 4);
    float4 m0 = *(const float4*)(wM + kt*32);
    float4 m1 = *(const float4*)(wM + kt*32 + 4);
    float4 d0 = *(const float4*)(wD + kt*32);
    float4 d1 = *(const float4*)(wD + kt*32 + 4);
    ss += q0.x*q0.x + q0.y*q0.y + q0.z*q0.z + q0.w*q0.w
        + q1.x*q1.x + q1.y*q1.y + q1.z*q1.z + q1.w*q1.w;
    lp += q0.x*s0.x + q0.y*s0.y + q0.z*s0.z + q0.w*s0.w
        + q1.x*s1.x + q1.y*s1.y + q1.z*s1.z + q1.w*s1.w;
    pm += q0.x*m0.x + q0.y*m0.y + q0.z*m0.z + q0.w*m0.w
        + q1.x*m1.x + q1.y*m1.y + q1.z*m1.z + q1.w*m1.w;
    pd += q0.x*d0.x + q0.y*d0.y + q0.z*d0.z + q0.w*d0.w
        + q1.x*d1.x + q1.y*d1.y + q1.z*d1.z + q1.w*d1.w;
  }
  // butterfly across the 4 quads -> per-token totals in every lane of the token
  #pragma unroll
  for (int mk=16; mk<64; mk<<=1){
    ss += __shfl_xor(ss, mk, 64); lp += __shfl_xor(lp, mk, 64);
    pm += __shfl_xor(pm, mk, 64); pd += __shfl_xor(pd, mk, 64);
  }
  float rs = 1.0f / sqrtf(ss*(1.0f/DIMX) + 1e-6f);
  float lr = 0.01f * sigmoidf_(rs*lp);
  float pmr = rs*pm, pdr = rs*pd;
  #pragma unroll
  for (int mk=1; mk<16; mk<<=1){
    pmr += __shfl_xor(pmr, mk, 64); pdr += __shfl_xor(pdr, mk, 64);
  }
  if (lane==0){
    momw[bt] = sigmoidf_(pmr*(1.0f/CHX));
    decw[bt] = 1.0f - sigmoidf_(pdr*(1.0f/CHX));
  }
  if (quad==0) lr_s[wv][nl] = lr;   // redistribute lr by token row later

  // ---- pass B: KV gemm, A straight from registers (seq re-read hits L1/L2)
  union BF { bf16x8 v; uint_t u[4]; };
  f32x4 kacc[8], vacc[8];
  #pragma unroll
  for (int s=0;s<8;s++){ kacc[s]=zero; vacc[s]=zero; }
  const ushort_t* wkvh = WkvT + (size_t)h*16*256*32;
  for (int kt=0; kt<16; kt++){
    float4 q0 = *(const float4*)(sq + kt*32);
    float4 q1 = *(const float4*)(sq + kt*32 + 4);
    BF af;
    af.u[0] = pk2(q0.x*rs, q0.y*rs);
    af.u[1] = pk2(q0.z*rs, q0.w*rs);
    af.u[2] = pk2(q1.x*rs, q1.y*rs);
    af.u[3] = pk2(q1.z*rs, q1.w*rs);
    const ushort_t* wb = wkvh + ((size_t)kt*256 + nl)*32 + quad*8;
    #pragma unroll
    for (int s=0; s<8; s++){
      bf16x8 Bk = *(const bf16x8*)(wb + (size_t)(s*16)*32);
      kacc[s] = __builtin_amdgcn_mfma_f32_16x16x32_bf16(af.v, Bk, kacc[s], 0,0,0);
      bf16x8 Bv = *(const bf16x8*)(wb + (size_t)(128 + s*16)*32);
      vacc[s] = __builtin_amdgcn_mfma_f32_16x16x32_bf16(af.v, Bv, vacc[s], 0,0,0);
    }
  }
  // k -> LDS (element (c = quad*4+r, p = s*16+nl))
  #pragma unroll
  for (int s=0;s<8;s++){
    #pragma unroll
    for (int r=0;r<4;r++)
      ksw[(quad*4+r)*PADF + s*16 + nl] = f2bf(kacc[s][r]);
  }

  // ---- gemm1: h = k @ w0  (A row c = nl, k p = kt*32+quad*8)
  const ushort_t* w0b = w0T + (size_t)bh*16384;
  f32x4 hacc[8];
  #pragma unroll
  for (int s=0;s<8;s++) hacc[s]=zero;
  for (int kt=0; kt<4; kt++){
    bf16x8 Af = *(const bf16x8*)&ksw[nl*PADF + kt*32 + quad*8];
    #pragma unroll
    for (int s=0; s<8; s++){
      bf16x8 Bf = *(const bf16x8*)&w0b[(size_t)(s*16+nl)*128 + kt*32 + quad*8];
      hacc[s] = __builtin_amdgcn_mfma_f32_16x16x32_bf16(Af, Bf, hacc[s], 0,0,0);
    }
  }
  float sp[8][4];
  #pragma unroll
  for (int s=0;s<8;s++){
    #pragma unroll
    for (int r=0;r<4;r++){
      float hh = hacc[s][r];
      float sg = sigmoidf_(hh);
      float a  = hh*sg;
      sp[s][r] = sg*(1.0f + hh*(1.0f-sg));
      asw[(quad*4+r)*PADF + s*16 + nl] = f2bf(a);
    }
  }

  // ---- gemm2: pred = a @ w1 ; dpred = 2/DH * lr * (pred - v)
  const ushort_t* w1tb = w1T + (size_t)bh*16384;
  f32x4 pacc[8];
  #pragma unroll
  for (int s=0;s<8;s++) pacc[s]=zero;
  for (int kt=0; kt<4; kt++){
    bf16x8 Af = *(const bf16x8*)&asw[nl*PADF + kt*32 + quad*8];
    #pragma unroll
    for (int s=0; s<8; s++){
      bf16x8 Bf = *(const bf16x8*)&w1tb[(size_t)(s*16+nl)*128 + kt*32 + quad*8];
      pacc[s] = __builtin_amdgcn_mfma_f32_16x16x32_bf16(Af, Bf, pacc[s], 0,0,0);
    }
  }
  float lrv[4];
  #pragma unroll
  for (int r=0;r<4;r++) lrv[r] = lr_s[wv][quad*4 + r];
  #pragma unroll
  for (int s=0;s<8;s++){
    #pragma unroll
    for (int r=0;r<4;r++){
      float dp = (2.0f/DHX)*lrv[r]*(pacc[s][r] - vacc[s][r]);
      dpw[(quad*4+r)*PADF + s*16 + nl] = f2bf(dp);
    }
  }

  // ---- gemm3: da = dpred @ w1^T ; dh0 = da * silu'(h)
  const ushort_t* w1nb = w1n + (size_t)bh*16384;
  f32x4 dacc[8];
  #pragma unroll
  for (int s=0;s<8;s++) dacc[s]=zero;
  for (int kt=0; kt<4; kt++){
    bf16x8 Af = *(const bf16x8*)&dpw[nl*PADF + kt*32 + quad*8];
    #pragma unroll
    for (int s=0; s<8; s++){
      bf16x8 Bf = *(const bf16x8*)&w1nb[(size_t)(s*16+nl)*128 + kt*32 + quad*8];
      dacc[s] = __builtin_amdgcn_mfma_f32_16x16x32_bf16(Af, Bf, dacc[s], 0,0,0);
    }
  }
  #pragma unroll
  for (int s=0;s<8;s++){
    #pragma unroll
    for (int r=0;r<4;r++)
      dhw[(quad*4+r)*PADF + s*16 + nl] = f2bf(dacc[s][r]*sp[s][r]);
  }

  // ---- pack: fac0 row p = {k c0..15 | a c0..15}, fac1 row p = {dh | dp}
  #pragma unroll
  for (int j=0;j<2;j++){
    int p = lane + j*64;
    ushort_t rowv[32];
    #pragma unroll
    for (int c=0;c<16;c++){ rowv[c] = ksw[c*PADF + p]; rowv[16+c] = asw[c*PADF + p]; }
    {
      ushort_t* dst = fac0 + ((size_t)bt*128 + p)*32;
      const uint4* rv = (const uint4*)rowv;
      uint4* dq = (uint4*)dst;
      dq[0]=rv[0]; dq[1]=rv[1]; dq[2]=rv[2]; dq[3]=rv[3];
    }
    #pragma unroll
    for (int c=0;c<16;c++){ rowv[c] = dhw[c*PADF + p]; rowv[16+c] = dpw[c*PADF + p]; }
    {
      ushort_t* dst = fac1 + ((size_t)bt*128 + p)*32;
      const uint4* rv = (const uint4*)rowv;
      uint4* dq = (uint4*)dst;
      dq[0]=rv[0]; dq[1]=rv[1]; dq[2]=rv[2]; dq[3]=rv[3];
    }
  }
}

// ---------------- K-scan3: barrier-free, LDS-free MFMA scan (unchanged) ----------------
__global__ __launch_bounds__(64) void k_scan3(const ushort_t* __restrict__ fac0,
    const ushort_t* __restrict__ fac1,
    const float* __restrict__ momw, const float* __restrict__ decw,
    float* __restrict__ out){
  int blk = blockIdx.x;
  int bh  = blk & 7;
  int jb  = (blk >> 3) & 7;
  int ig  = (blk >> 6) & 7;
  int mat = blk >> 9;
  int lane = threadIdx.x;
  int quad = lane >> 4, rrow = lane & 15;
  const f32x4 zero = {0.f,0.f,0.f,0.f};
  const bf16x8 fz = {0,0,0,0,0,0,0,0};

  size_t rowbase = (size_t)bh*NCX*128;
  const ushort_t* pa = fac0 + (rowbase + (size_t)(ig*16 + rrow))*32 + mat*16 + quad*8;
  const ushort_t* pb = fac1 + (rowbase + (size_t)(jb*16 + rrow))*32 + mat*16 + quad*8;
  bool act = (quad < 2);   // chunks 16..31 of the K dim are zero padding

  bf16x8 fa0=fz, fb0=fz, fa1=fz, fb1=fz;
  if (act){
    fa0 = *(const bf16x8*)(pa);
    fb0 = *(const bf16x8*)(pb);
    fa1 = *(const bf16x8*)(pa + 4096);
    fb1 = *(const bf16x8*)(pb + 4096);
  }

  f32x4 m_ = zero, u_ = zero;
  size_t obase = ((size_t)(mat*BHX + bh)*NCX)*((size_t)DHX*DHX)
               + (size_t)(ig*16 + quad*4)*DHX + (size_t)(jb*16 + rrow);
  const float* mop = momw + bh*NCX;
  const float* dep = decw + bh*NCX;

  for (int t=0; t<NCX; t+=2){
    bf16x8 na0=fz, nb0=fz, na1=fz, nb1=fz;
    if (act && (t+2 < NCX)){
      na0 = *(const bf16x8*)(pa + (size_t)(t+2)*4096);
      nb0 = *(const bf16x8*)(pb + (size_t)(t+2)*4096);
      na1 = *(const bf16x8*)(pa + (size_t)(t+3)*4096);
      nb1 = *(const bf16x8*)(pb + (size_t)(t+3)*4096);
    }
    float mo = mop[t], de = dep[t];
    f32x4 g = __builtin_amdgcn_mfma_f32_16x16x32_bf16(fa0, fb0, zero, 0,0,0);
    float* ob = out + obase + (size_t)t*(DHX*DHX);
    #pragma unroll
    for (int r=0;r<4;r++){
      m_[r] = mo*m_[r] - g[r];
      u_[r] = de*u_[r] + m_[r];
      ob[(size_t)r*DHX] = u_[r];
    }
    mo = mop[t+1]; de = dep[t+1];
    g = __builtin_amdgcn_mfma_f32_16x16x32_bf16(fa1, fb1, zero, 0,0,0);
    ob += (size_t)DHX*DHX;
    #pragma unroll
    for (int r=0;r<4;r++){
      m_[r] = mo*m_[r] - g[r];
      u_[r] = de*u_[r] + m_[r];
      ob[(size_t)r*DHX] = u_[r];
    }
    fa0=na0; fb0=nb0; fa1=na1; fb1=nb1;
  }
}

extern "C" void kernel_launch(void* const* d_in, const int* in_sizes, int n_in,
                              void* d_out, int out_size, void* d_ws, size_t ws_size,
                              hipStream_t stream) {
  (void)in_sizes; (void)n_in; (void)out_size; (void)ws_size;
  const float* seq   = (const float*)d_in[0];
  const float* scale = (const float*)d_in[1];
  const float* Wkv   = (const float*)d_in[2];
  const float* Wstep = (const float*)d_in[3];
  const float* Wmom  = (const float*)d_in[4];
  const float* Wdec  = (const float*)d_in[5];
  const float* w0    = (const float*)d_in[6];
  const float* w1    = (const float*)d_in[7];
  float* out = (float*)d_out;

  // workspace layout
  ushort_t* fac0 = (ushort_t*)d_ws;              // 4,194,304 ushorts (8 MB)
  ushort_t* fac1 = fac0 + 4194304;               // 4,194,304 ushorts
  ushort_t* WkvT = fac1 + 4194304;               // 524,288 ushorts
  ushort_t* w0T  = WkvT + 524288;                // 131,072 ushorts
  ushort_t* w1T  = w0T + 131072;                 // 131,072 ushorts
  ushort_t* w1n  = w1T + 131072;                 // 131,072 ushorts
  float*    momw = (float*)(w1n + 131072);       // 1,024 floats
  float*    decw = momw + 1024;                  // 1,024 floats
  float*    wfsS = decw + 1024;                  // 2,048 floats
  float*    wfsM = wfsS + 2048;                  // 2,048 floats
  float*    wfsD = wfsM + 2048;                  // 2,048 floats

  k_prep<<<dim3(73), dim3(256), 0, stream>>>(Wkv, w0, w1, scale, Wstep, Wmom, Wdec,
      WkvT, w0T, w1T, w1n, wfsS, wfsM, wfsD);
  k_fused3<<<dim3(256), dim3(256), 0, stream>>>(seq, wfsS, wfsM, wfsD,
      WkvT, w0T, w1T, w1n, fac0, fac1, momw, decw);
  k_scan3<<<dim3(1024), dim3(64), 0, stream>>>(fac0, fac1, momw, decw, out);
}